// Round 13
// baseline (496.535 us; speedup 1.0000x reference)
//
#include <hip/hip_runtime.h>

#define B_ 8
#define S_ 1025
#define D_ 768
#define H_ 12
#define KV_ 4
#define HD_ 64
#define NREP 3
#define SCALE_ 0.125f
#define EPS_ 1e-6f
#define SKP 1088   // padded key count (17*64)
#define PST 1096   // bf16 P row stride in LDS ushorts (2192 B)
#define PGS 1088   // packed global P row stride in ushorts (2176 B)
#define QBLK 16    // q-rows per block
#define NQT 65     // ceil(1025/16)
#define DYNLDS 35072  // 16*PST*2 bytes
#define NROWS (B_ * H_ * S_)   // 98400 attn rows

typedef __attribute__((ext_vector_type(8))) short bf16x8;
typedef __attribute__((ext_vector_type(4))) float f32x4;

__device__ __forceinline__ unsigned short f2bf(float f) {
  unsigned int u = __builtin_bit_cast(unsigned int, f);
  return (unsigned short)((u + 0x7FFFu + ((u >> 16) & 1u)) >> 16);
}
__device__ __forceinline__ unsigned int pk2(float a, float b) {
  return (unsigned int)f2bf(a) | ((unsigned int)f2bf(b) << 16);
}
__device__ __forceinline__ float bf2f(unsigned short u) {
  return __builtin_bit_cast(float, (unsigned int)u << 16);
}
__device__ __forceinline__ unsigned int cvtpk(float a, float b) {
  unsigned int r;
  asm("v_cvt_pk_bf16_f32 %0, %1, %2" : "=v"(r) : "v"(a), "v"(b));
  return r;
}

__device__ __forceinline__ void barrier_lgkm() {
  __builtin_amdgcn_sched_barrier(0);
  asm volatile("s_waitcnt lgkmcnt(0)" ::: "memory");
  __builtin_amdgcn_s_barrier();
  __builtin_amdgcn_sched_barrier(0);
}

// ---------------- casts ----------------
__global__ __launch_bounds__(256) void cast_x_kernel(const float* __restrict__ x,
                                                     unsigned short* __restrict__ xb, int n4) {
  int i = blockIdx.x * 256 + threadIdx.x;
  if (i >= n4) return;
  f32x4 v = *(const f32x4*)(x + (size_t)i * 4);
  uint2 o;
  o.x = pk2(v[0], v[1]);
  o.y = pk2(v[2], v[3]);
  *(uint2*)(xb + (size_t)i * 4) = o;
}

__global__ __launch_bounds__(256) void cast_wqkv_kernel(const float* __restrict__ Wq,
    const float* __restrict__ Wk, const float* __restrict__ Wv,
    unsigned short* __restrict__ WT) {
  int idx = blockIdx.x * 256 + threadIdx.x;  // = n*768 + k
  int n = idx / D_, k = idx % D_;
  float v;
  if (n < 768)       v = Wq[(size_t)k * 768 + n];
  else if (n < 1024) v = Wk[(size_t)k * 256 + (n - 768)];
  else               v = Wv[(size_t)k * 256 + (n - 1024)];
  WT[idx] = f2bf(v);
}

__global__ __launch_bounds__(256) void cast_wo_kernel(const float* __restrict__ Wo,
                                                      unsigned short* __restrict__ WT) {
  int idx = blockIdx.x * 256 + threadIdx.x;  // = n*768 + k
  int n = idx / D_, k = idx % D_;
  WT[idx] = f2bf(Wo[(size_t)k * D_ + n]);
}

// ---------------- GEMM: C[M][N] fp32 = A[M][K] bf16 @ BT[N][K] bf16 ----------------
#define BM 128
#define BN 128
#define BK 32
#define LSTR 40
__global__ __launch_bounds__(256) void gemm_bt(const unsigned short* __restrict__ A,
    const unsigned short* __restrict__ BT, float* __restrict__ C, int M, int N, int K) {
  __shared__ unsigned short As[BM * LSTR];
  __shared__ unsigned short Bs[BN * LSTR];
  const int nMt = (M + BM - 1) / BM;
  const int tm = blockIdx.x % nMt;
  const int tn = blockIdx.x / nMt;
  const int row0 = tm * BM, col0 = tn * BN;
  const int tid = threadIdx.x;
  const int l = tid & 63, w = tid >> 6;
  const int wr = (w >> 1) * 64, wc = (w & 1) * 64;
  const int lr = l & 15, lk = (l >> 4) * 8;
  f32x4 acc[4][4] = {};
  for (int kt = 0; kt < K; kt += BK) {
    __syncthreads();
#pragma unroll
    for (int i = 0; i < 2; ++i) {
      int c = tid + i * 256;
      int r = c >> 2;
      int ce = (c & 3) * 8;
      int gr = row0 + r; gr = gr < M ? gr : M - 1;
      bf16x8 va = *(const bf16x8*)(A + (size_t)gr * K + kt + ce);
      *(bf16x8*)&As[r * LSTR + ce] = va;
      bf16x8 vb = *(const bf16x8*)(BT + (size_t)(col0 + r) * K + kt + ce);
      *(bf16x8*)&Bs[r * LSTR + ce] = vb;
    }
    __syncthreads();
    bf16x8 af[4], bfr[4];
#pragma unroll
    for (int m = 0; m < 4; ++m)
      af[m] = *(const bf16x8*)&As[(wr + m * 16 + lr) * LSTR + lk];
#pragma unroll
    for (int n = 0; n < 4; ++n)
      bfr[n] = *(const bf16x8*)&Bs[(wc + n * 16 + lr) * LSTR + lk];
#pragma unroll
    for (int m = 0; m < 4; ++m)
#pragma unroll
      for (int n = 0; n < 4; ++n)
        acc[m][n] = __builtin_amdgcn_mfma_f32_16x16x32_bf16(af[m], bfr[n], acc[m][n], 0, 0, 0);
  }
  const int orow = (l >> 4) * 4;
#pragma unroll
  for (int m = 0; m < 4; ++m)
#pragma unroll
    for (int n = 0; n < 4; ++n)
#pragma unroll
      for (int r = 0; r < 4; ++r) {
        int row = row0 + wr + m * 16 + orow + r;
        int col = col0 + wc + n * 16 + lr;
        if (row < M) C[(size_t)row * N + col] = acc[m][n][r];
      }
}

// ---------------- QKV epilogue ----------------
__global__ __launch_bounds__(256) void qkv_epilogue(const float* __restrict__ QKV,
    const int* __restrict__ pos_ids, const int* __restrict__ ghp, const int* __restrict__ gwp,
    const float* __restrict__ qw, const float* __restrict__ kw,
    unsigned short* __restrict__ Qb, unsigned short* __restrict__ Kb,
    unsigned short* __restrict__ Vt) {
  if (blockIdx.x < B_ * KV_) {
    unsigned short* vp = Vt + (size_t)blockIdx.x * 64 * SKP;
    for (int idx = threadIdx.x; idx < 64 * 63; idx += 256) {
      int d = idx / 63, s = S_ + idx % 63;
      vp[d * SKP + s] = 0;
    }
  }
  int tok = blockIdx.x * 4 + (threadIdx.x >> 6);
  int l = threadIdx.x & 63;
  if (tok >= B_ * S_) return;
  int b = tok / S_, s = tok % S_;
  const float* rowp = QKV + (size_t)tok * 1280;
  bool rot = (s > 0);
  float cs = 1.f, sn = 0.f;
  if (rot) {
    int gh = ghp[0], gw = gwp[0];
    int pos = pos_ids[tok];
    int hi = (pos / gw) % gh;
    int wi = pos % gw;
    int pi = l >> 1;
    int j = pi < 16 ? pi : pi - 16;
    float invf = exp2f(-(float)j * (13.287712379549449f / 16.f));
    float ang = (pi < 16 ? (float)hi : (float)wi) * invf;
    cs = cosf(ang); sn = sinf(ang);
  }
#pragma unroll
  for (int h = 0; h < H_; ++h) {
    float x = rowp[h * 64 + l];
    float ss = x * x;
    for (int off = 32; off; off >>= 1) ss += __shfl_xor(ss, off);
    float xn = x * rsqrtf(ss * (1.f / 64.f) + EPS_) * qw[l];
    float o = xn;
    if (rot) {
      float p = __shfl_xor(xn, 1);
      o = (l & 1) ? (p * sn + xn * cs) : (xn * cs - p * sn);
    }
    o *= SCALE_;
    Qb[((size_t)(b * H_ + h) * S_ + s) * 64 + l] = f2bf(o);
  }
#pragma unroll
  for (int h = 0; h < KV_; ++h) {
    float x = rowp[768 + h * 64 + l];
    float ss = x * x;
    for (int off = 32; off; off >>= 1) ss += __shfl_xor(ss, off);
    float xn = x * rsqrtf(ss * (1.f / 64.f) + EPS_) * kw[l];
    float o = xn;
    if (rot) {
      float p = __shfl_xor(xn, 1);
      o = (l & 1) ? (p * sn + xn * cs) : (xn * cs - p * sn);
    }
    Kb[((size_t)(b * KV_ + h) * S_ + s) * 64 + l] = f2bf(o);
    float v = rowp[1024 + h * 64 + l];
    Vt[((size_t)(b * KV_ + h) * 64 + l) * SKP + s] = f2bf(v);
  }
}

// ============ attn CORE (kernel A): swapped QK^T, writes packed P + inv + ctx ============
__global__ __launch_bounds__(512, 4) void attn_core_kernel(const unsigned short* __restrict__ Qb,
    const unsigned short* __restrict__ Kb, const unsigned short* __restrict__ Vt,
    unsigned short* __restrict__ ctx, unsigned short* __restrict__ Pg,
    float* __restrict__ invg) {
  extern __shared__ unsigned short Psh[];   // [16][PST] unnormalized bf16 P
  __shared__ float partial[4][64][4];
  __shared__ float red[8][16];
  __shared__ unsigned short ctxs[16][64];
  int bid = blockIdx.x;
  int swz = (bid & 7) * 780 + (bid >> 3);
  int qt = swz % NQT;
  int h = (swz / NQT) % H_;
  int b = swz / (NQT * H_);
  int kvh = h / NREP;
  int q0 = qt * QBLK;
  int tid = threadIdx.x;
  int l = tid & 63, w = tid >> 6;
  int lr = l & 15, lk = (l >> 4) * 8;

  const unsigned short* Qbase = Qb + (size_t)(b * H_ + h) * S_ * 64;
  const unsigned short* Kbase = Kb + (size_t)(b * KV_ + kvh) * S_ * 64;
  const unsigned short* Vbase = Vt + (size_t)(b * KV_ + kvh) * 64 * SKP;
  const int rowbase = (b * H_ + h) * S_;

  int qrow = q0 + lr; if (qrow >= S_) qrow = S_ - 1;
  bf16x8 qf0 = *(const bf16x8*)(Qbase + (size_t)qrow * 64 + lk);
  bf16x8 qf1 = *(const bf16x8*)(Qbase + (size_t)qrow * 64 + 32 + lk);

  // Phase 1: swapped QK^T -> exp -> bf16 P into LDS (no max pass: |s|<=8 analytically)
  float psum = 0.f;
  {
    const int g4 = (l >> 4) * 4;
    const int kb = (w < 4) ? w * 144 : 576 + (w - 4) * 128;
#pragma unroll
    for (int j = 0; j < 9; ++j) {
      if (w < 4 || j < 8) {
        int kr = kb + j * 16 + lr; if (kr > 1024) kr = 1024;
        const unsigned short* kp = Kbase + (size_t)kr * 64;
        bf16x8 kf0 = *(const bf16x8*)(kp + lk);
        bf16x8 kf1 = *(const bf16x8*)(kp + 32 + lk);
        f32x4 acc = {};
        acc = __builtin_amdgcn_mfma_f32_16x16x32_bf16(kf0, qf0, acc, 0, 0, 0);
        acc = __builtin_amdgcn_mfma_f32_16x16x32_bf16(kf1, qf1, acc, 0, 0, 0);
        int key0 = kb + j * 16 + g4;
        float e0 = (key0     <= 1024) ? __expf(acc[0]) : 0.f;
        float e1 = (key0 + 1 <= 1024) ? __expf(acc[1]) : 0.f;
        float e2 = (key0 + 2 <= 1024) ? __expf(acc[2]) : 0.f;
        float e3 = (key0 + 3 <= 1024) ? __expf(acc[3]) : 0.f;
        psum += (e0 + e1) + (e2 + e3);
        uint2 pw; pw.x = cvtpk(e0, e1); pw.y = cvtpk(e2, e3);
        *(uint2*)&Psh[(size_t)lr * PST + key0] = pw;
      }
    }
  }
  psum += __shfl_xor(psum, 16);
  psum += __shfl_xor(psum, 32);
  if (l < 16) red[w][l] = psum;
  barrier_lgkm();                          // B1: P + red complete

  float invq;
  {
    float s = 0.f;
#pragma unroll
    for (int j2 = 0; j2 < 8; ++j2) s += red[j2][lr];
    invq = 1.f / s;
  }

  // inv dump: wave 0, lanes 0..15 each store their OWN invq (no shfl under divergence —
  // R12 bug was __shfl from an inactive lane inside `if (l==0)`, undefined data).
  if (w == 0 && l < 16) {
    int q = q0 + l;
    if (q < S_) invg[rowbase + q] = invq;
  }

  // Pg dump: wave w streams rows {w, w+8} coalesced (1KB requests).
#pragma unroll
  for (int rr = 0; rr < 2; ++rr) {
    int rowi = w + rr * 8;
    int q = q0 + rowi;
    if (q < S_) {
      const unsigned short* Prow = Psh + (size_t)rowi * PST;
      unsigned short* gp = Pg + (size_t)(rowbase + q) * PGS;
      bf16x8 v0 = *(const bf16x8*)&Prow[l * 8];
      bf16x8 v1 = *(const bf16x8*)&Prow[512 + l * 8];
      *(bf16x8*)&gp[l * 8] = v0;
      *(bf16x8*)&gp[512 + l * 8] = v1;
      if (l < 8) {
        bf16x8 v2 = *(const bf16x8*)&Prow[1024 + l * 8];
        *(bf16x8*)&gp[1024 + l * 8] = v2;
      }
    }
  }

  // PV
  f32x4 accv = {};
  {
    const int d0 = (w & 3) * 16;
    const int kh = (w >> 2) * 544;
    const int prow = lr * PST + kh;
    const unsigned short* vb = Vbase + (size_t)(d0 + lr) * SKP + kh;
#pragma unroll 4
    for (int kc = 0; kc < 17; ++kc) {
      bf16x8 pa = *(const bf16x8*)&Psh[prow + kc * 32 + lk];
      bf16x8 vf = *(const bf16x8*)(vb + kc * 32 + lk);
      accv = __builtin_amdgcn_mfma_f32_16x16x32_bf16(pa, vf, accv, 0, 0, 0);
    }
  }
  if (w >= 4) *(f32x4*)partial[w - 4][l] = accv;
  barrier_lgkm();
  if (w < 4) {
    accv += *(const f32x4*)partial[w][l];
    int rowb = (l >> 4) * 4;
    int d0 = (w & 3) * 16;
#pragma unroll
    for (int r = 0; r < 4; ++r) {
      float iv = __shfl(invq, rowb + r);   // full wave active (w<4 is wave-uniform)
      ctxs[rowb + r][d0 + lr] = f2bf(accv[r] * iv);
    }
  }
  barrier_lgkm();
  {
    int t = 2 * w + (l >> 5);
    int q = q0 + t;
    if (q < S_) {
      unsigned int u = *(const unsigned int*)&ctxs[t][2 * (l & 31)];
      *(unsigned int*)(ctx + (size_t)(b * S_ + q) * 768 + h * 64 + 2 * (l & 31)) = u;
    }
  }
}

// ============ attn EXPANDER (kernel B): fill-like linear streaming writer ============
__global__ __launch_bounds__(256) void attn_expand_kernel(const unsigned short* __restrict__ Pg,
    const float* __restrict__ invg, float* __restrict__ attn_out) {
  int t = threadIdx.x;
  for (int R = blockIdx.x; R < NROWS; R += gridDim.x) {
    const unsigned short* Prow = Pg + (size_t)R * PGS;
    float* gout = attn_out + (size_t)R * 1025;
    float rinv = invg[R];
    int a = (4 - (R & 3)) & 3;             // R*1025 ≡ R (mod 4)
    int nx4 = (1025 - a) >> 2;
    int tl = 1025 - a - 4 * nx4;
    if (t < a) gout[t] = bf2f(Prow[t]) * rinv;
    if (t < tl) { int idx = a + 4 * nx4 + t; gout[idx] = bf2f(Prow[idx]) * rinv; }
    int ch = t;
    if (ch < nx4) {
      f32x4 o;
      if (a == 0) {
        uint2 u = *(const uint2*)&Prow[4 * ch];
        o[0] = __builtin_bit_cast(float, u.x << 16) * rinv;
        o[1] = __builtin_bit_cast(float, u.x & 0xffff0000u) * rinv;
        o[2] = __builtin_bit_cast(float, u.y << 16) * rinv;
        o[3] = __builtin_bit_cast(float, u.y & 0xffff0000u) * rinv;
      } else if (a == 2) {
        unsigned int u0 = *(const unsigned int*)&Prow[4 * ch + 2];
        unsigned int u1 = *(const unsigned int*)&Prow[4 * ch + 4];
        o[0] = __builtin_bit_cast(float, u0 << 16) * rinv;
        o[1] = __builtin_bit_cast(float, u0 & 0xffff0000u) * rinv;
        o[2] = __builtin_bit_cast(float, u1 << 16) * rinv;
        o[3] = __builtin_bit_cast(float, u1 & 0xffff0000u) * rinv;
      } else if (a == 1) {
        uint2 d01 = *(const uint2*)&Prow[4 * ch];
        unsigned int d2 = *(const unsigned int*)&Prow[4 * ch + 4];
        unsigned int u0 = __builtin_amdgcn_alignbit(d01.y, d01.x, 16);
        unsigned int u1 = __builtin_amdgcn_alignbit(d2, d01.y, 16);
        o[0] = __builtin_bit_cast(float, u0 << 16) * rinv;
        o[1] = __builtin_bit_cast(float, u0 & 0xffff0000u) * rinv;
        o[2] = __builtin_bit_cast(float, u1 << 16) * rinv;
        o[3] = __builtin_bit_cast(float, u1 & 0xffff0000u) * rinv;
      } else { // a == 3
        unsigned int d0 = *(const unsigned int*)&Prow[4 * ch + 2];
        uint2 d12 = *(const uint2*)&Prow[4 * ch + 4];
        unsigned int u0 = __builtin_amdgcn_alignbit(d12.x, d0, 16);
        unsigned int u1 = __builtin_amdgcn_alignbit(d12.y, d12.x, 16);
        o[0] = __builtin_bit_cast(float, u0 << 16) * rinv;
        o[1] = __builtin_bit_cast(float, u0 & 0xffff0000u) * rinv;
        o[2] = __builtin_bit_cast(float, u1 << 16) * rinv;
        o[3] = __builtin_bit_cast(float, u1 & 0xffff0000u) * rinv;
      }
      *(f32x4*)(gout + a + 4 * ch) = o;
    }
  }
}

// ============ fallback monolith (R11, proven) ============
__global__ __launch_bounds__(512, 4) void attn_kernel(const unsigned short* __restrict__ Qb,
    const unsigned short* __restrict__ Kb, const unsigned short* __restrict__ Vt,
    unsigned short* __restrict__ ctx, float* __restrict__ attn_out) {
  extern __shared__ unsigned short Psh[];
  __shared__ float partial[4][64][4];
  __shared__ float red[8][16];
  __shared__ unsigned short ctxs[16][64];
  int bid = blockIdx.x;
  int swz = (bid & 7) * 780 + (bid >> 3);
  int qt = swz % NQT;
  int h = (swz / NQT) % H_;
  int b = swz / (NQT * H_);
  int kvh = h / NREP;
  int q0 = qt * QBLK;
  int tid = threadIdx.x;
  int l = tid & 63, w = tid >> 6;
  int lr = l & 15, lk = (l >> 4) * 8;

  const unsigned short* Qbase = Qb + (size_t)(b * H_ + h) * S_ * 64;
  const unsigned short* Kbase = Kb + (size_t)(b * KV_ + kvh) * S_ * 64;
  const unsigned short* Vbase = Vt + (size_t)(b * KV_ + kvh) * 64 * SKP;

  int qrow = q0 + lr; if (qrow >= S_) qrow = S_ - 1;
  bf16x8 qf0 = *(const bf16x8*)(Qbase + (size_t)qrow * 64 + lk);
  bf16x8 qf1 = *(const bf16x8*)(Qbase + (size_t)qrow * 64 + 32 + lk);

  float psum = 0.f;
  {
    const int g4 = (l >> 4) * 4;
    const int kb = (w < 4) ? w * 144 : 576 + (w - 4) * 128;
#pragma unroll
    for (int j = 0; j < 9; ++j) {
      if (w < 4 || j < 8) {
        int kr = kb + j * 16 + lr; if (kr > 1024) kr = 1024;
        const unsigned short* kp = Kbase + (size_t)kr * 64;
        bf16x8 kf0 = *(const bf16x8*)(kp + lk);
        bf16x8 kf1 = *(const bf16x8*)(kp + 32 + lk);
        f32x4 acc = {};
        acc = __builtin_amdgcn_mfma_f32_16x16x32_bf16(kf0, qf0, acc, 0, 0, 0);
        acc = __builtin_amdgcn_mfma_f32_16x16x32_bf16(kf1, qf1, acc, 0, 0, 0);
        int key0 = kb + j * 16 + g4;
        float e0 = (key0     <= 1024) ? __expf(acc[0]) : 0.f;
        float e1 = (key0 + 1 <= 1024) ? __expf(acc[1]) : 0.f;
        float e2 = (key0 + 2 <= 1024) ? __expf(acc[2]) : 0.f;
        float e3 = (key0 + 3 <= 1024) ? __expf(acc[3]) : 0.f;
        psum += (e0 + e1) + (e2 + e3);
        uint2 pw; pw.x = cvtpk(e0, e1); pw.y = cvtpk(e2, e3);
        *(uint2*)&Psh[(size_t)lr * PST + key0] = pw;
      }
    }
  }
  psum += __shfl_xor(psum, 16);
  psum += __shfl_xor(psum, 32);
  if (l < 16) red[w][l] = psum;
  barrier_lgkm();

  float invq;
  {
    float s = 0.f;
#pragma unroll
    for (int j2 = 0; j2 < 8; ++j2) s += red[j2][lr];
    invq = 1.f / s;
  }

  f32x4 accv = {};
  {
    const int d0 = (w & 3) * 16;
    const int kh = (w >> 2) * 544;
    const int prow = lr * PST + kh;
    const unsigned short* vb = Vbase + (size_t)(d0 + lr) * SKP + kh;
#pragma unroll 4
    for (int kc = 0; kc < 17; ++kc) {
      bf16x8 pa = *(const bf16x8*)&Psh[prow + kc * 32 + lk];
      bf16x8 vf = *(const bf16x8*)(vb + kc * 32 + lk);
      accv = __builtin_amdgcn_mfma_f32_16x16x32_bf16(pa, vf, accv, 0, 0, 0);
    }
  }
  if (w >= 4) *(f32x4*)partial[w - 4][l] = accv;
  barrier_lgkm();
  if (w < 4) {
    accv += *(const f32x4*)partial[w][l];
    int rowb = (l >> 4) * 4;
    int d0 = (w & 3) * 16;
#pragma unroll
    for (int r = 0; r < 4; ++r) {
      float iv = __shfl(invq, rowb + r);
      ctxs[rowb + r][d0 + lr] = f2bf(accv[r] * iv);
    }
  }
  barrier_lgkm();
  {
    int t = 2 * w + (l >> 5);
    int q = q0 + t;
    if (q < S_) {
      unsigned int u = *(const unsigned int*)&ctxs[t][2 * (l & 31)];
      *(unsigned int*)(ctx + (size_t)(b * S_ + q) * 768 + h * 64 + 2 * (l & 31)) = u;
    }
  }

#pragma unroll
  for (int rr = 0; rr < 2; ++rr) {
    int rowi = w + rr * 8;
    int q = q0 + rowi;
    if (q < S_) {
      float rinv = __shfl(invq, rowi);
      const unsigned short* Prow = Psh + (size_t)rowi * PST;
      float* gout = attn_out + ((size_t)(b * H_ + h) * S_ + q) * S_;
      int a = (4 - (q & 3)) & 3;
      int nx4 = (1025 - a) >> 2;
      int tl = 1025 - a - 4 * nx4;
      if (l < a) gout[l] = bf2f(Prow[l]) * rinv;
      if (l < tl) { int idx = a + 4 * nx4 + l; gout[idx] = bf2f(Prow[idx]) * rinv; }
      if (a == 0) {
#pragma unroll
        for (int c = 0; c < 4; ++c) {
          int ch = c * 64 + l;
          if (ch < nx4) {
            uint2 u = *(const uint2*)&Prow[4 * ch];
            f32x4 o;
            o[0] = __builtin_bit_cast(float, u.x << 16) * rinv;
            o[1] = __builtin_bit_cast(float, u.x & 0xffff0000u) * rinv;
            o[2] = __builtin_bit_cast(float, u.y << 16) * rinv;
            o[3] = __builtin_bit_cast(float, u.y & 0xffff0000u) * rinv;
            *(f32x4*)(gout + 4 * ch) = o;
          }
        }
      } else if (a == 2) {
#pragma unroll
        for (int c = 0; c < 4; ++c) {
          int ch = c * 64 + l;
          if (ch < nx4) {
            unsigned int u0 = *(const unsigned int*)&Prow[4 * ch + 2];
            unsigned int u1 = *(const unsigned int*)&Prow[4 * ch + 4];
            f32x4 o;
            o[0] = __builtin_bit_cast(float, u0 << 16) * rinv;
            o[1] = __builtin_bit_cast(float, u0 & 0xffff0000u) * rinv;
            o[2] = __builtin_bit_cast(float, u1 << 16) * rinv;
            o[3] = __builtin_bit_cast(float, u1 & 0xffff0000u) * rinv;
            *(f32x4*)(gout + 2 + 4 * ch) = o;
          }
        }
      } else if (a == 1) {
#pragma unroll
        for (int c = 0; c < 4; ++c) {
          int ch = c * 64 + l;
          if (ch < nx4) {
            uint2 d01 = *(const uint2*)&Prow[4 * ch];
            unsigned int d2 = *(const unsigned int*)&Prow[4 * ch + 4];
            unsigned int u0 = __builtin_amdgcn_alignbit(d01.y, d01.x, 16);
            unsigned int u1 = __builtin_amdgcn_alignbit(d2, d01.y, 16);
            f32x4 o;
            o[0] = __builtin_bit_cast(float, u0 << 16) * rinv;
            o[1] = __builtin_bit_cast(float, u0 & 0xffff0000u) * rinv;
            o[2] = __builtin_bit_cast(float, u1 << 16) * rinv;
            o[3] = __builtin_bit_cast(float, u1 & 0xffff0000u) * rinv;
            *(f32x4*)(gout + 1 + 4 * ch) = o;
          }
        }
      } else {
#pragma unroll
        for (int c = 0; c < 4; ++c) {
          int ch = c * 64 + l;
          if (ch < nx4) {
            unsigned int d0 = *(const unsigned int*)&Prow[4 * ch + 2];
            uint2 d12 = *(const uint2*)&Prow[4 * ch + 4];
            unsigned int u0 = __builtin_amdgcn_alignbit(d12.x, d0, 16);
            unsigned int u1 = __builtin_amdgcn_alignbit(d12.y, d12.x, 16);
            f32x4 o;
            o[0] = __builtin_bit_cast(float, u0 << 16) * rinv;
            o[1] = __builtin_bit_cast(float, u0 & 0xffff0000u) * rinv;
            o[2] = __builtin_bit_cast(float, u1 << 16) * rinv;
            o[3] = __builtin_bit_cast(float, u1 & 0xffff0000u) * rinv;
            *(f32x4*)(gout + 3 + 4 * ch) = o;
          }
        }
      }
    }
  }
}

// ---------------- launch ----------------
extern "C" void kernel_launch(void* const* d_in, const int* in_sizes, int n_in,
                              void* d_out, int out_size, void* d_ws, size_t ws_size,
                              hipStream_t stream) {
  const float* hidden = (const float*)d_in[0];
  const int* pos_ids = (const int*)d_in[2];
  const int* ghp = (const int*)d_in[3];
  const int* gwp = (const int*)d_in[4];
  const float* Wq = (const float*)d_in[5];
  const float* Wk = (const float*)d_in[6];
  const float* Wv = (const float*)d_in[7];
  const float* Wo = (const float*)d_in[8];
  const float* qnw = (const float*)d_in[9];
  const float* knw = (const float*)d_in[10];

  char* ws = (char*)d_ws;
  unsigned short* Xb    = (unsigned short*)ws;                   // 12,595,200
  unsigned short* WqkvT = (unsigned short*)(ws + 12595200);      //  1,966,080
  unsigned short* WoT   = (unsigned short*)(ws + 14561280);      //  1,179,648
  float*          QKV   = (float*)(ws + 15740928);               // 41,984,000
  unsigned short* ctx   = (unsigned short*)(ws + 15740928);      // alias (after QKV consumed)
  unsigned short* Qb    = (unsigned short*)(ws + 57724928);      // 12,595,200
  unsigned short* Kb    = (unsigned short*)(ws + 70320128);      //  4,198,400
  unsigned short* Vt    = (unsigned short*)(ws + 74518528);      //  4,456,448
  unsigned short* Pg    = (unsigned short*)(ws + 78974976);      // 214,118,400
  float*          invg  = (float*)(ws + 293093376);              //     393,600
  const size_t NEED_SPLIT = 293486976;

  float* out0 = (float*)d_out;
  float* attn_out = out0 + (size_t)B_ * S_ * D_;

  cast_x_kernel<<<6150, 256, 0, stream>>>(hidden, Xb, 1574400);
  cast_wqkv_kernel<<<3840, 256, 0, stream>>>(Wq, Wk, Wv, WqkvT);
  cast_wo_kernel<<<2304, 256, 0, stream>>>(Wo, WoT);

  gemm_bt<<<65 * 10, 256, 0, stream>>>(Xb, WqkvT, QKV, B_ * S_, 1280, D_);

  qkv_epilogue<<<2050, 256, 0, stream>>>(QKV, pos_ids, ghp, gwp, qnw, knw, Qb, Kb, Vt);

  if (ws_size >= NEED_SPLIT) {
    hipFuncSetAttribute((const void*)attn_core_kernel,
                        hipFuncAttributeMaxDynamicSharedMemorySize, DYNLDS);
    attn_core_kernel<<<B_ * H_ * NQT, 512, DYNLDS, stream>>>(Qb, Kb, Vt, ctx, Pg, invg);
    attn_expand_kernel<<<4096, 256, 0, stream>>>(Pg, invg, attn_out);
  } else {
    hipFuncSetAttribute((const void*)attn_kernel,
                        hipFuncAttributeMaxDynamicSharedMemorySize, DYNLDS);
    attn_kernel<<<B_ * H_ * NQT, 512, DYNLDS, stream>>>(Qb, Kb, Vt, ctx, attn_out);
  }

  gemm_bt<<<65 * 6, 256, 0, stream>>>(ctx, WoT, out0, B_ * S_, D_, D_);
}

// Round 15
// 332.344 us; speedup vs baseline: 1.4940x; 1.4940x over previous
//
#include <hip/hip_runtime.h>

#define B_ 8
#define S_ 1025
#define D_ 768
#define H_ 12
#define KV_ 4
#define HD_ 64
#define NREP 3
#define SCALE_ 0.125f
#define EPS_ 1e-6f
#define SKP 1088   // padded key count (17*64)
#define PST 1096   // bf16 P row stride in LDS ushorts (2192 B)
#define QBLK 16    // q-rows per block
#define NQT 65     // ceil(1025/16)
#define DYNLDS 35072  // 16*PST*2 bytes

typedef __attribute__((ext_vector_type(8))) short bf16x8;
typedef __attribute__((ext_vector_type(4))) float f32x4;

__device__ __forceinline__ unsigned short f2bf(float f) {
  unsigned int u = __builtin_bit_cast(unsigned int, f);
  return (unsigned short)((u + 0x7FFFu + ((u >> 16) & 1u)) >> 16);
}
__device__ __forceinline__ unsigned int pk2(float a, float b) {
  return (unsigned int)f2bf(a) | ((unsigned int)f2bf(b) << 16);
}
__device__ __forceinline__ float bf2f(unsigned short u) {
  return __builtin_bit_cast(float, (unsigned int)u << 16);
}
__device__ __forceinline__ unsigned int cvtpk(float a, float b) {
  unsigned int r;
  asm("v_cvt_pk_bf16_f32 %0, %1, %2" : "=v"(r) : "v"(a), "v"(b));
  return r;
}
// async global->LDS, 16B per lane (HW: wave-uniform LDS base + lane*16; our layout is
// chunk-linear so per-lane dest == base + lane*16 exactly). m97-proven pattern.
__device__ __forceinline__ void gload16(const void* g, void* l) {
  __builtin_amdgcn_global_load_lds(
      (const __attribute__((address_space(1))) unsigned int*)g,
      (__attribute__((address_space(3))) unsigned int*)l, 16, 0, 0);
}

__device__ __forceinline__ void barrier_lgkm() {
  __builtin_amdgcn_sched_barrier(0);
  asm volatile("s_waitcnt lgkmcnt(0)" ::: "memory");
  __builtin_amdgcn_s_barrier();
  __builtin_amdgcn_sched_barrier(0);
}

// ---------------- fused casts (one launch) ----------------
#define CX_BLK 6150   // 1,574,400 f32x4 groups / 256  (R14 bug: had 1538 -> 3/4 of X unconverted)
#define CW_BLK 3840   // 983040/256
#define CO_BLK 2304   // 589824/256
__global__ __launch_bounds__(256) void cast_all_kernel(const float* __restrict__ x,
    const float* __restrict__ Wq, const float* __restrict__ Wk, const float* __restrict__ Wv,
    const float* __restrict__ Wo, unsigned short* __restrict__ xb,
    unsigned short* __restrict__ WqkvT, unsigned short* __restrict__ WoT) {
  int bid = blockIdx.x;
  if (bid < CX_BLK) {
    int i = bid * 256 + threadIdx.x;
    if (i < 1574400) {
      f32x4 v = *(const f32x4*)(x + (size_t)i * 4);
      uint2 o;
      o.x = pk2(v[0], v[1]);
      o.y = pk2(v[2], v[3]);
      *(uint2*)(xb + (size_t)i * 4) = o;
    }
  } else if (bid < CX_BLK + CW_BLK) {
    int idx = (bid - CX_BLK) * 256 + threadIdx.x;   // < 983040 = 1280*768
    int n = idx / D_, k = idx % D_;
    float v;
    if (n < 768)       v = Wq[(size_t)k * 768 + n];
    else if (n < 1024) v = Wk[(size_t)k * 256 + (n - 768)];
    else               v = Wv[(size_t)k * 256 + (n - 1024)];
    WqkvT[idx] = f2bf(v);
  } else {
    int idx = (bid - CX_BLK - CW_BLK) * 256 + threadIdx.x;  // < 589824 = 768*768
    int n = idx / D_, k = idx % D_;
    WoT[idx] = f2bf(Wo[(size_t)k * D_ + n]);
  }
}

// ---------------- GEMM: C[M][N] fp32 = A[M][K] bf16 @ BT[N][K] bf16 ----------------
// m97 structure: 128x128 tile, BK=32, linear LDS, global_load_lds width=16 staging,
// 2-barrier K-loop (compiler emits vmcnt(0) before s_barrier -> tiles ready).
#define BM 128
#define BN 128
#define BK 32
__global__ __launch_bounds__(256) void gemm_bt(const unsigned short* __restrict__ A,
    const unsigned short* __restrict__ BT, float* __restrict__ C, int M, int N, int K) {
  __shared__ unsigned short As[BM * BK];   // 8KB, chunk-linear: chunk c = row c>>2, cols (c&3)*8..
  __shared__ unsigned short Bs[BN * BK];
  const int nMt = (M + BM - 1) / BM;
  const int tm = blockIdx.x % nMt;
  const int tn = blockIdx.x / nMt;
  const int row0 = tm * BM, col0 = tn * BN;
  const int tid = threadIdx.x;
  const int l = tid & 63, w = tid >> 6;
  const int wr = (w >> 1) * 64, wc = (w & 1) * 64;
  const int lr = l & 15, lk = (l >> 4) * 8;
  // staging chunk ids (2 per tile per thread); per-wave LDS dest = base + lane*16
  const int c0 = tid, c1 = tid + 256;
  const int r0 = c0 >> 2, e0 = (c0 & 3) * 8;
  const int r1 = c1 >> 2, e1 = (c1 & 3) * 8;
  int ga0 = row0 + r0; if (ga0 >= M) ga0 = M - 1;
  int ga1 = row0 + r1; if (ga1 >= M) ga1 = M - 1;
  const int gb0 = col0 + r0, gb1 = col0 + r1;     // N is a multiple of 128: in-bounds
  f32x4 acc[4][4] = {};
  for (int kt = 0; kt < K; kt += BK) {
    __syncthreads();                               // LDS safe to overwrite
    gload16(A + (size_t)ga0 * K + kt + e0, &As[c0 * 8]);
    gload16(A + (size_t)ga1 * K + kt + e1, &As[c1 * 8]);
    gload16(BT + (size_t)gb0 * K + kt + e0, &Bs[c0 * 8]);
    gload16(BT + (size_t)gb1 * K + kt + e1, &Bs[c1 * 8]);
    __syncthreads();                               // vmcnt(0) drained -> tiles resident
    bf16x8 af[4], bfr[4];
#pragma unroll
    for (int m = 0; m < 4; ++m)
      af[m] = *(const bf16x8*)&As[(wr + m * 16 + lr) * BK + lk];
#pragma unroll
    for (int n = 0; n < 4; ++n)
      bfr[n] = *(const bf16x8*)&Bs[(wc + n * 16 + lr) * BK + lk];
#pragma unroll
    for (int m = 0; m < 4; ++m)
#pragma unroll
      for (int n = 0; n < 4; ++n)
        acc[m][n] = __builtin_amdgcn_mfma_f32_16x16x32_bf16(af[m], bfr[n], acc[m][n], 0, 0, 0);
  }
  const int orow = (l >> 4) * 4;
#pragma unroll
  for (int m = 0; m < 4; ++m)
#pragma unroll
    for (int n = 0; n < 4; ++n)
#pragma unroll
      for (int r = 0; r < 4; ++r) {
        int row = row0 + wr + m * 16 + orow + r;
        int col = col0 + wc + n * 16 + lr;
        if (row < M) C[(size_t)row * N + col] = acc[m][n][r];
      }
}

// ---------------- QKV epilogue: rmsnorm + rope + layouts (+ V pad zeroing) ----------------
__global__ __launch_bounds__(256) void qkv_epilogue(const float* __restrict__ QKV,
    const int* __restrict__ pos_ids, const int* __restrict__ ghp, const int* __restrict__ gwp,
    const float* __restrict__ qw, const float* __restrict__ kw,
    unsigned short* __restrict__ Qb, unsigned short* __restrict__ Kb,
    unsigned short* __restrict__ Vt) {
  if (blockIdx.x < B_ * KV_) {
    unsigned short* vp = Vt + (size_t)blockIdx.x * 64 * SKP;
    for (int idx = threadIdx.x; idx < 64 * 63; idx += 256) {
      int d = idx / 63, s = S_ + idx % 63;
      vp[d * SKP + s] = 0;
    }
  }
  int tok = blockIdx.x * 4 + (threadIdx.x >> 6);
  int l = threadIdx.x & 63;
  if (tok >= B_ * S_) return;
  int b = tok / S_, s = tok % S_;
  const float* rowp = QKV + (size_t)tok * 1280;
  bool rot = (s > 0);
  float cs = 1.f, sn = 0.f;
  if (rot) {
    int gh = ghp[0], gw = gwp[0];
    int pos = pos_ids[tok];
    int hi = (pos / gw) % gh;
    int wi = pos % gw;
    int pi = l >> 1;
    int j = pi < 16 ? pi : pi - 16;
    float invf = exp2f(-(float)j * (13.287712379549449f / 16.f));
    float ang = (pi < 16 ? (float)hi : (float)wi) * invf;
    cs = cosf(ang); sn = sinf(ang);
  }
#pragma unroll
  for (int h = 0; h < H_; ++h) {
    float x = rowp[h * 64 + l];
    float ss = x * x;
    for (int off = 32; off; off >>= 1) ss += __shfl_xor(ss, off);
    float xn = x * rsqrtf(ss * (1.f / 64.f) + EPS_) * qw[l];
    float o = xn;
    if (rot) {
      float p = __shfl_xor(xn, 1);
      o = (l & 1) ? (p * sn + xn * cs) : (xn * cs - p * sn);
    }
    o *= SCALE_;
    Qb[((size_t)(b * H_ + h) * S_ + s) * 64 + l] = f2bf(o);
  }
#pragma unroll
  for (int h = 0; h < KV_; ++h) {
    float x = rowp[768 + h * 64 + l];
    float ss = x * x;
    for (int off = 32; off; off >>= 1) ss += __shfl_xor(ss, off);
    float xn = x * rsqrtf(ss * (1.f / 64.f) + EPS_) * kw[l];
    float o = xn;
    if (rot) {
      float p = __shfl_xor(xn, 1);
      o = (l & 1) ? (p * sn + xn * cs) : (xn * cs - p * sn);
    }
    Kb[((size_t)(b * KV_ + h) * S_ + s) * 64 + l] = f2bf(o);
    float v = rowp[1024 + h * 64 + l];
    Vt[((size_t)(b * KV_ + h) * 64 + l) * SKP + s] = f2bf(v);
  }
}

// ---------------- fused attention (R11 monolith, proven @340us) ----------------
__global__ __launch_bounds__(512, 4) void attn_kernel(const unsigned short* __restrict__ Qb,
    const unsigned short* __restrict__ Kb, const unsigned short* __restrict__ Vt,
    unsigned short* __restrict__ ctx, float* __restrict__ attn_out) {
  extern __shared__ unsigned short Psh[];
  __shared__ float partial[4][64][4];
  __shared__ float red[8][16];
  __shared__ unsigned short ctxs[16][64];
  int bid = blockIdx.x;
  int swz = (bid & 7) * 780 + (bid >> 3);
  int qt = swz % NQT;
  int h = (swz / NQT) % H_;
  int b = swz / (NQT * H_);
  int kvh = h / NREP;
  int q0 = qt * QBLK;
  int tid = threadIdx.x;
  int l = tid & 63, w = tid >> 6;
  int lr = l & 15, lk = (l >> 4) * 8;

  const unsigned short* Qbase = Qb + (size_t)(b * H_ + h) * S_ * 64;
  const unsigned short* Kbase = Kb + (size_t)(b * KV_ + kvh) * S_ * 64;
  const unsigned short* Vbase = Vt + (size_t)(b * KV_ + kvh) * 64 * SKP;

  int qrow = q0 + lr; if (qrow >= S_) qrow = S_ - 1;
  bf16x8 qf0 = *(const bf16x8*)(Qbase + (size_t)qrow * 64 + lk);
  bf16x8 qf1 = *(const bf16x8*)(Qbase + (size_t)qrow * 64 + 32 + lk);

  float psum = 0.f;
  {
    const int g4 = (l >> 4) * 4;
    const int kb = (w < 4) ? w * 144 : 576 + (w - 4) * 128;
#pragma unroll
    for (int j = 0; j < 9; ++j) {
      if (w < 4 || j < 8) {
        int kr = kb + j * 16 + lr; if (kr > 1024) kr = 1024;
        const unsigned short* kp = Kbase + (size_t)kr * 64;
        bf16x8 kf0 = *(const bf16x8*)(kp + lk);
        bf16x8 kf1 = *(const bf16x8*)(kp + 32 + lk);
        f32x4 acc = {};
        acc = __builtin_amdgcn_mfma_f32_16x16x32_bf16(kf0, qf0, acc, 0, 0, 0);
        acc = __builtin_amdgcn_mfma_f32_16x16x32_bf16(kf1, qf1, acc, 0, 0, 0);
        int key0 = kb + j * 16 + g4;
        float e0 = (key0     <= 1024) ? __expf(acc[0]) : 0.f;
        float e1 = (key0 + 1 <= 1024) ? __expf(acc[1]) : 0.f;
        float e2 = (key0 + 2 <= 1024) ? __expf(acc[2]) : 0.f;
        float e3 = (key0 + 3 <= 1024) ? __expf(acc[3]) : 0.f;
        psum += (e0 + e1) + (e2 + e3);
        uint2 pw; pw.x = cvtpk(e0, e1); pw.y = cvtpk(e2, e3);
        *(uint2*)&Psh[(size_t)lr * PST + key0] = pw;
      }
    }
  }
  psum += __shfl_xor(psum, 16);
  psum += __shfl_xor(psum, 32);
  if (l < 16) red[w][l] = psum;
  barrier_lgkm();

  float invq;
  {
    float s = 0.f;
#pragma unroll
    for (int j2 = 0; j2 < 8; ++j2) s += red[j2][lr];
    invq = 1.f / s;
  }

  f32x4 accv = {};
  {
    const int d0 = (w & 3) * 16;
    const int kh = (w >> 2) * 544;
    const int prow = lr * PST + kh;
    const unsigned short* vb = Vbase + (size_t)(d0 + lr) * SKP + kh;
#pragma unroll 4
    for (int kc = 0; kc < 17; ++kc) {
      bf16x8 pa = *(const bf16x8*)&Psh[prow + kc * 32 + lk];
      bf16x8 vf = *(const bf16x8*)(vb + kc * 32 + lk);
      accv = __builtin_amdgcn_mfma_f32_16x16x32_bf16(pa, vf, accv, 0, 0, 0);
    }
  }
  if (w >= 4) *(f32x4*)partial[w - 4][l] = accv;
  barrier_lgkm();
  if (w < 4) {
    accv += *(const f32x4*)partial[w][l];
    int rowb = (l >> 4) * 4;
    int d0 = (w & 3) * 16;
#pragma unroll
    for (int r = 0; r < 4; ++r) {
      float iv = __shfl(invq, rowb + r);
      ctxs[rowb + r][d0 + lr] = f2bf(accv[r] * iv);
    }
  }
  barrier_lgkm();
  {
    int t = 2 * w + (l >> 5);
    int q = q0 + t;
    if (q < S_) {
      unsigned int u = *(const unsigned int*)&ctxs[t][2 * (l & 31)];
      *(unsigned int*)(ctx + (size_t)(b * S_ + q) * 768 + h * 64 + 2 * (l & 31)) = u;
    }
  }

#pragma unroll
  for (int rr = 0; rr < 2; ++rr) {
    int rowi = w + rr * 8;
    int q = q0 + rowi;
    if (q < S_) {
      float rinv = __shfl(invq, rowi);
      const unsigned short* Prow = Psh + (size_t)rowi * PST;
      float* gout = attn_out + ((size_t)(b * H_ + h) * S_ + q) * S_;
      int a = (4 - (q & 3)) & 3;
      int nx4 = (1025 - a) >> 2;
      int tl = 1025 - a - 4 * nx4;
      if (l < a) gout[l] = bf2f(Prow[l]) * rinv;
      if (l < tl) { int idx = a + 4 * nx4 + l; gout[idx] = bf2f(Prow[idx]) * rinv; }
      if (a == 0) {
#pragma unroll
        for (int c = 0; c < 4; ++c) {
          int ch = c * 64 + l;
          if (ch < nx4) {
            uint2 u = *(const uint2*)&Prow[4 * ch];
            f32x4 o;
            o[0] = __builtin_bit_cast(float, u.x << 16) * rinv;
            o[1] = __builtin_bit_cast(float, u.x & 0xffff0000u) * rinv;
            o[2] = __builtin_bit_cast(float, u.y << 16) * rinv;
            o[3] = __builtin_bit_cast(float, u.y & 0xffff0000u) * rinv;
            *(f32x4*)(gout + 4 * ch) = o;
          }
        }
      } else if (a == 2) {
#pragma unroll
        for (int c = 0; c < 4; ++c) {
          int ch = c * 64 + l;
          if (ch < nx4) {
            unsigned int u0 = *(const unsigned int*)&Prow[4 * ch + 2];
            unsigned int u1 = *(const unsigned int*)&Prow[4 * ch + 4];
            f32x4 o;
            o[0] = __builtin_bit_cast(float, u0 << 16) * rinv;
            o[1] = __builtin_bit_cast(float, u0 & 0xffff0000u) * rinv;
            o[2] = __builtin_bit_cast(float, u1 << 16) * rinv;
            o[3] = __builtin_bit_cast(float, u1 & 0xffff0000u) * rinv;
            *(f32x4*)(gout + 2 + 4 * ch) = o;
          }
        }
      } else if (a == 1) {
#pragma unroll
        for (int c = 0; c < 4; ++c) {
          int ch = c * 64 + l;
          if (ch < nx4) {
            uint2 d01 = *(const uint2*)&Prow[4 * ch];
            unsigned int d2 = *(const unsigned int*)&Prow[4 * ch + 4];
            unsigned int u0 = __builtin_amdgcn_alignbit(d01.y, d01.x, 16);
            unsigned int u1 = __builtin_amdgcn_alignbit(d2, d01.y, 16);
            f32x4 o;
            o[0] = __builtin_bit_cast(float, u0 << 16) * rinv;
            o[1] = __builtin_bit_cast(float, u0 & 0xffff0000u) * rinv;
            o[2] = __builtin_bit_cast(float, u1 << 16) * rinv;
            o[3] = __builtin_bit_cast(float, u1 & 0xffff0000u) * rinv;
            *(f32x4*)(gout + 1 + 4 * ch) = o;
          }
        }
      } else {
#pragma unroll
        for (int c = 0; c < 4; ++c) {
          int ch = c * 64 + l;
          if (ch < nx4) {
            unsigned int d0 = *(const unsigned int*)&Prow[4 * ch + 2];
            uint2 d12 = *(const uint2*)&Prow[4 * ch + 4];
            unsigned int u0 = __builtin_amdgcn_alignbit(d12.x, d0, 16);
            unsigned int u1 = __builtin_amdgcn_alignbit(d12.y, d12.x, 16);
            f32x4 o;
            o[0] = __builtin_bit_cast(float, u0 << 16) * rinv;
            o[1] = __builtin_bit_cast(float, u0 & 0xffff0000u) * rinv;
            o[2] = __builtin_bit_cast(float, u1 << 16) * rinv;
            o[3] = __builtin_bit_cast(float, u1 & 0xffff0000u) * rinv;
            *(f32x4*)(gout + 3 + 4 * ch) = o;
          }
        }
      }
    }
  }
}

// ---------------- launch ----------------
extern "C" void kernel_launch(void* const* d_in, const int* in_sizes, int n_in,
                              void* d_out, int out_size, void* d_ws, size_t ws_size,
                              hipStream_t stream) {
  const float* hidden = (const float*)d_in[0];
  const int* pos_ids = (const int*)d_in[2];
  const int* ghp = (const int*)d_in[3];
  const int* gwp = (const int*)d_in[4];
  const float* Wq = (const float*)d_in[5];
  const float* Wk = (const float*)d_in[6];
  const float* Wv = (const float*)d_in[7];
  const float* Wo = (const float*)d_in[8];
  const float* qnw = (const float*)d_in[9];
  const float* knw = (const float*)d_in[10];

  char* ws = (char*)d_ws;
  unsigned short* Xb    = (unsigned short*)ws;                   // 12,595,200
  unsigned short* WqkvT = (unsigned short*)(ws + 12595200);      //  1,966,080
  unsigned short* WoT   = (unsigned short*)(ws + 14561280);      //  1,179,648
  float*          QKV   = (float*)(ws + 15740928);               // 41,984,000
  unsigned short* ctx   = (unsigned short*)(ws + 15740928);      // alias (after QKV consumed)
  unsigned short* Qb    = (unsigned short*)(ws + 57724928);      // 12,595,200
  unsigned short* Kb    = (unsigned short*)(ws + 70320128);      //  4,198,400
  unsigned short* Vt    = (unsigned short*)(ws + 74518528);      //  4,456,448

  float* out0 = (float*)d_out;
  float* attn_out = out0 + (size_t)B_ * S_ * D_;

  cast_all_kernel<<<CX_BLK + CW_BLK + CO_BLK, 256, 0, stream>>>(
      hidden, Wq, Wk, Wv, Wo, Xb, WqkvT, WoT);

  gemm_bt<<<65 * 10, 256, 0, stream>>>(Xb, WqkvT, QKV, B_ * S_, 1280, D_);

  qkv_epilogue<<<2050, 256, 0, stream>>>(QKV, pos_ids, ghp, gwp, qnw, knw, Qb, Kb, Vt);

  hipFuncSetAttribute((const void*)attn_kernel,
                      hipFuncAttributeMaxDynamicSharedMemorySize, DYNLDS);
  attn_kernel<<<B_ * H_ * NQT, 512, DYNLDS, stream>>>(Qb, Kb, Vt, ctx, attn_out);

  gemm_bt<<<65 * 6, 256, 0, stream>>>(ctx, WoT, out0, B_ * S_, D_, D_);
}